// Round 5
// baseline (639.070 us; speedup 1.0000x reference)
//
#include <hip/hip_runtime.h>
#include <math.h>

#define NTOK   32768
#define DDIM   2048
#define NEXP   64
#define TOKB   64              // tokens per block (= lanes per wave)
#define BLOCK  512             // 8 waves
#define EPW    8               // experts per wave (8 waves x 8 = 64)
#define DCH    64              // d-values per round
#define ROUNDS (DDIM / DCH)    // 32
#define RPQ    (ROUNDS / 4)    // 8 rounds per 512-d quarter
#define J4     (DCH / 4)       // 16 float4 per 64-d chunk

struct Stage {
    float4 xs[2][J4][TOKB];    // x chunk, d-major, XOR-swizzled: [j4][tok^j4]
    float4 ws[2][NEXP][J4];    // W chunk, transposed: [e][j4] (16B-aligned rows)
};
union Smem {
    Stage st;                                                   // 64 KB
    struct { float logit[TOKB][NEXP + 1];
             float prob [TOKB][NEXP + 1]; } ep;                 // 33 KB
};

// One-time (per launch) transpose of kernel_DE [2048][64] -> wT [64][2048] in d_ws.
__global__ void transpose_w(const float* __restrict__ wde, float* __restrict__ wt) {
    int idx = blockIdx.x * 256 + threadIdx.x;   // 131072 elements
    int e = idx >> 11;                          // / 2048
    int d = idx & 2047;
    wt[idx] = wde[d * NEXP + e];                // write coalesced; read L2-served
}

__global__ __launch_bounds__(BLOCK, 4)
void router_kernel(const float* __restrict__ x, const float* __restrict__ wt,
                   float* __restrict__ out) {
    __shared__ Smem sm;
    const int tid  = threadIdx.x;
    const int lane = tid & 63;        // lane = token within block
    const int w    = tid >> 6;        // wave -> experts [8w, 8w+8)
    const int tok0 = blockIdx.x * TOKB;

    // accq[q][k]: partial logit for (token=lane, expert=8w+k), 512-d quarter q.
    // Ascending-d fmaf within quarter + (q0+q1)+(q2+q3) combine == R4's
    // validated chain -> bitwise-identical logits -> identical top-k indices.
    float accq[4][EPW];
    #pragma unroll
    for (int q = 0; q < 4; ++q)
        #pragma unroll
        for (int k = 0; k < EPW; ++k) accq[q][k] = 0.0f;

    // staging coords: f = tid + 512*i over 64 rows x 16 float4
    int s_row[2], s_j[2];
    #pragma unroll
    for (int i = 0; i < 2; ++i) {
        int f = tid + BLOCK * i;
        s_row[i] = f >> 4;            // token (x) or expert (W)
        s_j[i]   = f & 15;            // float4 column within 64-d chunk
    }

    float4 sx[2], sw[2];
    auto issue = [&](int r) {
        #pragma unroll
        for (int i = 0; i < 2; ++i) {
            sx[i] = *(const float4*)(x  + (size_t)(tok0 + s_row[i]) * DDIM + r * DCH + 4 * s_j[i]);
            sw[i] = *(const float4*)(wt + (size_t)s_row[i] * DDIM          + r * DCH + 4 * s_j[i]);
        }
    };

    issue(0);
    #pragma unroll
    for (int q = 0; q < 4; ++q) {               // unrolled: accq[q] stays in regs
        for (int rr = 0; rr < RPQ; ++rr) {
            const int r = q * RPQ + rr;
            const int b = r & 1;
            #pragma unroll
            for (int i = 0; i < 2; ++i) {
                sm.st.xs[b][s_j[i]][s_row[i] ^ s_j[i]] = sx[i];  // XOR swizzle
                sm.st.ws[b][s_row[i]][s_j[i]]          = sw[i];
            }
            __syncthreads();                    // dbuf makes 1 barrier/round safe
            if (r + 1 < ROUNDS) issue(r + 1);   // global prefetch under compute

            #pragma unroll
            for (int j4 = 0; j4 < J4; ++j4) {
                float4 xq = sm.st.xs[b][j4][lane ^ j4];   // per-lane, conflict-free b128
                #pragma unroll
                for (int k = 0; k < EPW; ++k) {
                    float4 wq = sm.st.ws[b][EPW * w + k][j4];  // wave-uniform broadcast
                    accq[q][k] = fmaf(xq.x, wq.x, accq[q][k]);
                    accq[q][k] = fmaf(xq.y, wq.y, accq[q][k]);
                    accq[q][k] = fmaf(xq.z, wq.z, accq[q][k]);
                    accq[q][k] = fmaf(xq.w, wq.w, accq[q][k]);
                }
            }
        }
    }
    __syncthreads();   // all reads of st done before union reuse

    // combine quarters exactly like R4: (q0+q1)+(q2+q3); deposit logits
    #pragma unroll
    for (int k = 0; k < EPW; ++k) {
        float a01 = accq[0][k] + accq[1][k];
        float a23 = accq[2][k] + accq[3][k];
        sm.ep.logit[lane][EPW * w + k] = a01 + a23;  // stride 65 -> conflict-free
    }
    __syncthreads();

    if (tid < 64) {
        const int tok = tok0 + tid;

        // softmax over 64 experts; LDS-resident (no per-thread lg[64] -> no spills).
        // Same op order as R4: m = lg[0]; fmax ascending; s summed ascending.
        float m = sm.ep.logit[tid][0];
        for (int e = 1; e < NEXP; ++e) m = fmaxf(m, sm.ep.logit[tid][e]);
        float s = 0.0f;
        for (int e = 0; e < NEXP; ++e) {
            float v = expf(sm.ep.logit[tid][e] - m);
            s += v;
            sm.ep.prob[tid][e] = v;
        }

        // top-8, strict '>' keeps lowest index on ties (lax.top_k semantics)
        unsigned long long chosen = 0ull;
        float wv[8], wi[8];
        #pragma unroll
        for (int k = 0; k < 8; ++k) {
            float best = -1.0f; int bi = 0;
            for (int e = 0; e < NEXP; ++e) {
                float pv = sm.ep.prob[tid][e];
                bool ok = (((chosen >> e) & 1ull) == 0ull) && (pv > best);
                best = ok ? pv : best;
                bi   = ok ? e : bi;
            }
            chosen |= (1ull << bi);
            wv[k] = best;
            wi[k] = (float)bi;
        }

        // second softmax over the 8 selected gating probabilities
        float p0 = wv[0] / s;
        float e2[8]; float s2 = 0.0f;
        #pragma unroll
        for (int k = 0; k < 8; ++k) { e2[k] = expf(wv[k] / s - p0); s2 += e2[k]; }

        float4* ow = (float4*)(out + (size_t)tok * 8);
        ow[0] = make_float4(e2[0]/s2, e2[1]/s2, e2[2]/s2, e2[3]/s2);
        ow[1] = make_float4(e2[4]/s2, e2[5]/s2, e2[6]/s2, e2[7]/s2);
        float4* oi = (float4*)(out + (size_t)NTOK * 8 + (size_t)tok * 8);
        oi[0] = make_float4(wi[0], wi[1], wi[2], wi[3]);
        oi[1] = make_float4(wi[4], wi[5], wi[6], wi[7]);
    }
}

extern "C" void kernel_launch(void* const* d_in, const int* in_sizes, int n_in,
                              void* d_out, int out_size, void* d_ws, size_t ws_size,
                              hipStream_t stream) {
    const float* x   = (const float*)d_in[0];
    const float* wde = (const float*)d_in[1];
    float* wt        = (float*)d_ws;      // 512 KB transposed W
    float* out       = (float*)d_out;
    transpose_w<<<dim3(DDIM * NEXP / 256), dim3(256), 0, stream>>>(wde, wt);
    router_kernel<<<dim3(NTOK / TOKB), dim3(BLOCK), 0, stream>>>(x, wt, out);
}